// Round 12
// baseline (95.301 us; speedup 1.0000x reference)
//
#include <hip/hip_runtime.h>

#define N_NODES 50000
#define N_EDGES 800000
#define DIM 128
#define M_PAD 50048                 // 1564 binBC blocks * 32 rows

#define BNODES 64                   // nodes per bucket (dst>>6)
#define NBUCK 782                   // ceil(N_NODES / 64)
#define SLACK 1280                  // per-bucket capacity (mean 1023, sigma 32)
#define EPB   4096                  // edges per binA block
#define NBLKA ((N_EDGES + EPB - 1) / EPB)   // 196
#define SPLIT 2                     // binBC blocks per bucket

#define M_TILE 32                   // binBC: rows per block
#define MW 2                        // binBC: 16-row m-frags per wave

typedef __attribute__((ext_vector_type(8))) short bf16x8;
typedef __attribute__((ext_vector_type(4))) float f32x4;
typedef __attribute__((ext_vector_type(2))) unsigned int u32x2;

// ws layout (bytes):
//   int gcur[1024]                    @ 0            (4,096)
//   u32 buf[NBUCK*SLACK]              @ 4,096        (4,003,840)
//   bf16 xh[M_PAD][128]               @ 4,007,936    (12,812,288)
//   bf16 WhT[128][256]                @ 16,820,224   (65,536)   -> total 16.9 MB
#define WS_BUF_OFF 4096
#define WS_XH_OFF  (WS_BUF_OFF + (size_t)NBUCK * SLACK * 4)
#define WS_WT_OFF  (WS_XH_OFF + (size_t)M_PAD * DIM * 2)

static __device__ __forceinline__ unsigned short f2b(float f) {
    unsigned int x = __float_as_uint(f);
    x += 0x7fffu + ((x >> 16) & 1u);
    return (unsigned short)(x >> 16);
}
static __device__ __forceinline__ float blo(unsigned int v) {
    return __uint_as_float(v << 16);
}
static __device__ __forceinline__ float bhi(unsigned int v) {
    return __uint_as_float(v & 0xffff0000u);
}

// ---------------- prepA: binA (blocks 0..195, starts first) + cast + WhT -------
#define CAST_BLOCKS 6250            // 6.4M floats / 4 / 256
#define WT_BLOCKS 64

__global__ __launch_bounds__(256) void prepA_kernel(
    const float* __restrict__ x,
    const float* __restrict__ Wl,
    const float* __restrict__ Wr,
    const int* __restrict__ src,
    const int* __restrict__ dst,
    unsigned short* __restrict__ xh,
    unsigned short* __restrict__ WhT,
    int* __restrict__ gcur,
    unsigned int* __restrict__ buf)
{
    __shared__ unsigned int img[EPB];        // 16 KB (binA blocks only)
    __shared__ int hist[NBUCK];
    __shared__ int lbase[NBUCK];
    __shared__ int gbase[NBUCK];

    const int blk = blockIdx.x;
    const int tid = threadIdx.x;

    if (blk >= NBLKA) {
        int b = blk - NBLKA;
        if (b < CAST_BLOCKS) {               // cast x -> bf16
            int i = b * 256 + tid;
            float4 v = reinterpret_cast<const float4*>(x)[i];
            ushort4 h;
            h.x = f2b(v.x); h.y = f2b(v.y); h.z = f2b(v.z); h.w = f2b(v.w);
            reinterpret_cast<ushort4*>(xh)[i] = h;
        } else {                             // build WhT
            int idx = (b - CAST_BLOCKS) * 256 + tid;   // k*128+n over [128][128]
            int n = idx & 127;
            int k = idx >> 7;
            WhT[n * 256 + k]       = f2b(Wl[idx]);
            WhT[n * 256 + 128 + k] = f2b(Wr[idx]);
        }
        return;
    }

    // ---- binA: block-local counting sort into global bucket runs
    const int e0 = blk * EPB;
    const int n = min(EPB, N_EDGES - e0);

    for (int i = tid; i < NBUCK; i += 256) hist[i] = 0;
    __syncthreads();
    for (int i = tid; i < n; i += 256)
        atomicAdd(&hist[dst[e0 + i] >> 6], 1);
    __syncthreads();
    if (tid < 64) {                          // excl. scan of hist[0..781]
        int c0 = tid * 13;
        int v[13];
        int s = 0;
        #pragma unroll
        for (int j = 0; j < 13; ++j) {
            int idx = c0 + j;
            v[j] = (idx < NBUCK) ? hist[idx] : 0;
            s += v[j];
        }
        int incl = s;
        #pragma unroll
        for (int d = 1; d < 64; d <<= 1) {
            int t = __shfl_up(incl, d, 64);
            if (tid >= d) incl += t;
        }
        int run = incl - s;
        #pragma unroll
        for (int j = 0; j < 13; ++j) {
            int idx = c0 + j;
            if (idx < NBUCK) lbase[idx] = run;
            run += v[j];
        }
    }
    __syncthreads();
    for (int i = tid; i < NBUCK; i += 256) {
        int c = hist[i];
        gbase[i] = i * SLACK + (c ? atomicAdd(&gcur[i], c) : 0);
        hist[i] = 0;                         // reuse as rank cursor
    }
    __syncthreads();
    for (int i = tid; i < n; i += 256) {
        int d = dst[e0 + i];
        int s = src[e0 + i];
        int b = d >> 6;
        int r = atomicAdd(&hist[b], 1);
        img[lbase[b] + r] = (unsigned int)s | ((unsigned int)d << 16);
    }
    __syncthreads();
    for (int i = tid; i < n; i += 256) {
        unsigned int v = img[i];
        int b = (int)(v >> 16) >> 6;
        int pos = gbase[b] + (i - lbase[b]);
        if (pos < (b + 1) * SLACK) buf[pos] = v;   // overflow drops, not corrupts
    }
}

// ---------------- binBC: LDS CSR + quad x2-gather-mean + MFMA GEMM + LN + ReLU -
__global__ __launch_bounds__(256) void binBC_kernel(
    const unsigned int* __restrict__ buf,
    const int* __restrict__ gcur,
    const unsigned short* __restrict__ xh,
    const unsigned short* __restrict__ WhT,
    const float* __restrict__ bl,
    const float* __restrict__ gamma,
    const float* __restrict__ beta,
    float* __restrict__ out)
{
    __shared__ unsigned int ebuf[SLACK];              // 5,120 B packed edges
    __shared__ unsigned short csr[SLACK + 16];        // 2,592 B local CSR, zeroed
    __shared__ int dhist[BNODES];
    __shared__ int dbase[BNODES];
    __shared__ int dcur[BNODES];
    __shared__ unsigned short aggh[M_TILE][DIM + 8];  // 8,704 B bf16 agg tile
    __shared__ float sRed[M_TILE][4][2];              // 1,024 B LN partials

    const int tid = threadIdx.x;
    const int w = tid >> 6;
    const int lane = tid & 63;
    const int r16 = lane & 15;
    const int kg = lane >> 4;
    const int b = blockIdx.x / SPLIT;            // bucket
    const int half = blockIdx.x % SPLIT;         // node slice
    const int rb = blockIdx.x * M_TILE;          // global row base
    const int cnt = min(gcur[b], SLACK);
    const unsigned int* bp = buf + (size_t)b * SLACK;

    // ---- local CSR build (bucket-wide, 64 nodes); csr zero-init for safe clamp
    if (tid < BNODES) { dhist[tid] = 0; dcur[tid] = 0; }
    for (int i = tid; i < (SLACK + 16) / 2; i += 256)
        reinterpret_cast<unsigned int*>(csr)[i] = 0;
    for (int i = tid; i < cnt; i += 256) ebuf[i] = bp[i];
    __syncthreads();
    for (int i = tid; i < cnt; i += 256)
        atomicAdd(&dhist[(ebuf[i] >> 16) & 63], 1);
    __syncthreads();
    if (tid < 64) {                              // scan 64 degree values
        int v = dhist[tid];
        int incl = v;
        #pragma unroll
        for (int d = 1; d < 64; d <<= 1) {
            int t = __shfl_up(incl, d, 64);
            if (tid >= d) incl += t;
        }
        dbase[tid] = incl - v;
    }
    __syncthreads();
    for (int i = tid; i < cnt; i += 256) {
        unsigned int v = ebuf[i];
        int d = (v >> 16) & 63;
        int r = atomicAdd(&dcur[d], 1);
        csr[dbase[d] + r] = (unsigned short)(v & 0xFFFFu);
    }
    __syncthreads();

    // ---- quad-gather, dwordx2: wave w owns rows w+4i+16q; per quad 4 nodes x
    //      8 dwordx2 insts = 64 rows in flight. Lane: h2 = edge-slot parity,
    //      sub covers features 4*sub..4*sub+3 (8B). Cross-half reduce at end.
    const char* xb = reinterpret_cast<const char*>(xh);
    const int h2 = lane >> 5;
    const int sub = lane & 31;
    const unsigned loff = (unsigned)(sub * 8);

    for (int q = 0; q < 2; ++q) {
        int lnl[4], deg[4], st[4], dm[4];
        #pragma unroll
        for (int i = 0; i < 4; ++i) {
            lnl[i] = w + 4 * i + 16 * q;
            int ln = half * M_TILE + lnl[i];
            int node = b * BNODES + ln;
            deg[i] = (node < N_NODES) ? dhist[ln] : 0;
            st[i] = dbase[ln];
            dm[i] = max(deg[i] - 1, 0);
        }
        u32x2 vv[4][8];
        #pragma unroll
        for (int i = 0; i < 4; ++i)
            #pragma unroll
            for (int t = 0; t < 8; ++t) {
                int e = t * 2 + h2;
                unsigned off = (unsigned)csr[st[i] + min(e, dm[i])] * 256u + loff;
                vv[i][t] = *reinterpret_cast<const u32x2*>(xb + off);
            }
        float a0[4], a1[4], a2[4], a3[4];
        #pragma unroll
        for (int i = 0; i < 4; ++i) { a0[i] = a1[i] = a2[i] = a3[i] = 0.f; }
        #pragma unroll
        for (int i = 0; i < 4; ++i)
            #pragma unroll
            for (int t = 0; t < 8; ++t) {
                int e = t * 2 + h2;
                if (e < deg[i]) {
                    a0[i] += blo(vv[i][t].x); a1[i] += bhi(vv[i][t].x);
                    a2[i] += blo(vv[i][t].y); a3[i] += bhi(vv[i][t].y);
                }
            }
        // tails (deg > 16): 8-edge x2 batches
        #pragma unroll
        for (int i = 0; i < 4; ++i) {
            for (int base = 16; base < deg[i]; base += 8) {
                u32x2 u[4];
                #pragma unroll
                for (int t = 0; t < 4; ++t) {
                    int e = base + t * 2 + h2;
                    unsigned off = (unsigned)csr[st[i] + min(e, dm[i])] * 256u + loff;
                    u[t] = *reinterpret_cast<const u32x2*>(xb + off);
                }
                #pragma unroll
                for (int t = 0; t < 4; ++t) {
                    int e = base + t * 2 + h2;
                    if (e < deg[i]) {
                        a0[i] += blo(u[t].x); a1[i] += bhi(u[t].x);
                        a2[i] += blo(u[t].y); a3[i] += bhi(u[t].y);
                    }
                }
            }
        }
        // cross-half reduce + bf16 pack + LDS write (lanes 0..31)
        #pragma unroll
        for (int i = 0; i < 4; ++i) {
            a0[i] += __shfl_xor(a0[i], 32);
            a1[i] += __shfl_xor(a1[i], 32);
            a2[i] += __shfl_xor(a2[i], 32);
            a3[i] += __shfl_xor(a3[i], 32);
            float inv = 1.0f / (float)max(deg[i], 1);
            if (h2 == 0) {
                u32x2 pk;
                pk.x = (unsigned)f2b(a0[i] * inv) | ((unsigned)f2b(a1[i] * inv) << 16);
                pk.y = (unsigned)f2b(a2[i] * inv) | ((unsigned)f2b(a3[i] * inv) << 16);
                *reinterpret_cast<u32x2*>(&aggh[lnl[i]][sub * 4]) = pk;
            }
        }
    }
    __syncthreads();

    // ---- MFMA GEMM: 32 rows x 128 cols, K=256 (A: LDS agg ++ own xh rows)
    f32x4 acc[MW][2];
    #pragma unroll
    for (int m = 0; m < MW; ++m)
        #pragma unroll
        for (int f = 0; f < 2; ++f)
            acc[m][f] = (f32x4){0.f, 0.f, 0.f, 0.f};

    #pragma unroll
    for (int kf = 0; kf < 8; ++kf) {
        bf16x8 a[MW];
        bf16x8 bfk[2];
        #pragma unroll
        for (int f = 0; f < 2; ++f)
            bfk[f] = *reinterpret_cast<const bf16x8*>(
                WhT + (w * 32 + f * 16 + r16) * 256 + kf * 32 + kg * 8);
        if (kf < 4) {
            #pragma unroll
            for (int m = 0; m < MW; ++m)
                a[m] = *reinterpret_cast<const bf16x8*>(
                    &aggh[m * 16 + r16][kf * 32 + kg * 8]);
        } else {
            #pragma unroll
            for (int m = 0; m < MW; ++m)
                a[m] = *reinterpret_cast<const bf16x8*>(
                    xh + (size_t)(rb + m * 16 + r16) * DIM + (kf - 4) * 32 + kg * 8);
        }
        #pragma unroll
        for (int m = 0; m < MW; ++m)
            #pragma unroll
            for (int f = 0; f < 2; ++f)
                acc[m][f] = __builtin_amdgcn_mfma_f32_16x16x32_bf16(
                    a[m], bfk[f], acc[m][f], 0, 0, 0);
    }

    // ---- bias + LayerNorm + ReLU epilogue
    float blv[2], gav[2], bev[2];
    #pragma unroll
    for (int f = 0; f < 2; ++f) {
        int col = w * 32 + f * 16 + r16;
        blv[f] = bl[col]; gav[f] = gamma[col]; bev[f] = beta[col];
    }
    #pragma unroll
    for (int m = 0; m < MW; ++m)
        #pragma unroll
        for (int r = 0; r < 4; ++r) {
            float v0 = acc[m][0][r] + blv[0];
            float v1 = acc[m][1][r] + blv[1];
            acc[m][0][r] = v0; acc[m][1][r] = v1;
            float s = v0 + v1;
            float q = v0 * v0 + v1 * v1;
            #pragma unroll
            for (int d = 1; d < 16; d <<= 1) {
                s += __shfl_xor(s, d, 16);
                q += __shfl_xor(q, d, 16);
            }
            if (r16 == 0) {
                sRed[m * 16 + kg * 4 + r][w][0] = s;
                sRed[m * 16 + kg * 4 + r][w][1] = q;
            }
        }
    __syncthreads();

    #pragma unroll
    for (int m = 0; m < MW; ++m)
        #pragma unroll
        for (int r = 0; r < 4; ++r) {
            int lr = m * 16 + kg * 4 + r;
            float S = sRed[lr][0][0] + sRed[lr][1][0] + sRed[lr][2][0] + sRed[lr][3][0];
            float Q = sRed[lr][0][1] + sRed[lr][1][1] + sRed[lr][2][1] + sRed[lr][3][1];
            float mean = S * (1.0f / 128.0f);
            float var = Q * (1.0f / 128.0f) - mean * mean;
            float rstd = rsqrtf(var + 1e-5f);
            int row = rb + lr;
            if (row < N_NODES) {
                #pragma unroll
                for (int f = 0; f < 2; ++f) {
                    float o = (acc[m][f][r] - mean) * rstd * gav[f] + bev[f];
                    out[(size_t)row * DIM + w * 32 + f * 16 + r16] = fmaxf(o, 0.f);
                }
            }
        }
}

extern "C" void kernel_launch(void* const* d_in, const int* in_sizes, int n_in,
                              void* d_out, int out_size, void* d_ws, size_t ws_size,
                              hipStream_t stream) {
    const float* x     = (const float*)d_in[0];
    const int*   ei    = (const int*)d_in[1];
    const float* Wl    = (const float*)d_in[2];
    const float* bl    = (const float*)d_in[3];
    const float* Wr    = (const float*)d_in[4];
    const float* gamma = (const float*)d_in[5];
    const float* beta  = (const float*)d_in[6];
    float* out = (float*)d_out;
    int*           gcur = (int*)d_ws;
    unsigned int*  buf  = (unsigned int*)((char*)d_ws + WS_BUF_OFF);
    unsigned short* xh  = (unsigned short*)((char*)d_ws + WS_XH_OFF);
    unsigned short* WhT = (unsigned short*)((char*)d_ws + WS_WT_OFF);

    const int* src = ei;
    const int* dst = ei + N_EDGES;

    (void)hipMemsetAsync(gcur, 0, 1024 * sizeof(int), stream);

    prepA_kernel<<<NBLKA + CAST_BLOCKS + WT_BLOCKS, 256, 0, stream>>>(
        x, Wl, Wr, src, dst, xh, WhT, gcur, buf);
    binBC_kernel<<<NBUCK * SPLIT, 256, 0, stream>>>(
        buf, gcur, xh, WhT, bl, gamma, beta, out);
}

// Round 13
// 77.991 us; speedup vs baseline: 1.2220x; 1.2220x over previous
//
#include <hip/hip_runtime.h>

#define N_NODES 50000
#define N_EDGES 800000
#define DIM 128
#define M_PAD 50048                 // 1564 binBC blocks * 32 rows

#define BNODES 64                   // nodes per bucket (dst>>6)
#define NBUCK 782                   // ceil(N_NODES / 64)
#define SLACK 1280                  // per-bucket capacity (mean 1023, sigma 32)
#define EPB   4096                  // edges per binA block
#define NBLKA ((N_EDGES + EPB - 1) / EPB)   // 196
#define SPLIT 2                     // binBC blocks per bucket

#define M_TILE 32                   // binBC: rows per block
#define MW 2                        // binBC: 16-row m-frags per wave

typedef __attribute__((ext_vector_type(8))) short bf16x8;
typedef __attribute__((ext_vector_type(4))) float f32x4;

// ws layout (bytes):
//   int gcur[1024]                    @ 0            (4,096)
//   u32 buf[NBUCK*SLACK]              @ 4,096        (4,003,840)
//   bf16 xh[M_PAD][128]               @ 4,007,936    (12,812,288)
//   bf16 WhT[128][256]                @ 16,820,224   (65,536)   -> total 16.9 MB
#define WS_BUF_OFF 4096
#define WS_XH_OFF  (WS_BUF_OFF + (size_t)NBUCK * SLACK * 4)
#define WS_WT_OFF  (WS_XH_OFF + (size_t)M_PAD * DIM * 2)

static __device__ __forceinline__ unsigned short f2b(float f) {
    unsigned int x = __float_as_uint(f);
    x += 0x7fffu + ((x >> 16) & 1u);
    return (unsigned short)(x >> 16);
}
static __device__ __forceinline__ float blo(unsigned int v) {
    return __uint_as_float(v << 16);
}
static __device__ __forceinline__ float bhi(unsigned int v) {
    return __uint_as_float(v & 0xffff0000u);
}

// ---------------- prepA: binA (blocks 0..195, starts first) + cast + WhT -------
// cast: 4 float4 per thread (4 loads in flight) -> BW-bound, not latency-bound
#define N_F4 (N_NODES * DIM / 4)    // 1,600,000 float4s
#define CAST_BLOCKS 1563            // ceil(N_F4 / 1024)
#define WT_BLOCKS 64

__global__ __launch_bounds__(256) void prepA_kernel(
    const float* __restrict__ x,
    const float* __restrict__ Wl,
    const float* __restrict__ Wr,
    const int* __restrict__ src,
    const int* __restrict__ dst,
    unsigned short* __restrict__ xh,
    unsigned short* __restrict__ WhT,
    int* __restrict__ gcur,
    unsigned int* __restrict__ buf)
{
    __shared__ unsigned int img[EPB];        // 16 KB (binA blocks only)
    __shared__ int hist[NBUCK];
    __shared__ int lbase[NBUCK];
    __shared__ int gbase[NBUCK];

    const int blk = blockIdx.x;
    const int tid = threadIdx.x;

    if (blk >= NBLKA) {
        int b = blk - NBLKA;
        if (b < CAST_BLOCKS) {               // cast x -> bf16, 4 f4 per thread
            int base = b * 1024 + tid;
            #pragma unroll
            for (int r = 0; r < 4; ++r) {
                int i = base + r * 256;
                if (i < N_F4) {
                    float4 v = reinterpret_cast<const float4*>(x)[i];
                    ushort4 h;
                    h.x = f2b(v.x); h.y = f2b(v.y); h.z = f2b(v.z); h.w = f2b(v.w);
                    reinterpret_cast<ushort4*>(xh)[i] = h;
                }
            }
        } else {                             // build WhT
            int idx = (b - CAST_BLOCKS) * 256 + tid;   // k*128+n over [128][128]
            int n = idx & 127;
            int k = idx >> 7;
            WhT[n * 256 + k]       = f2b(Wl[idx]);
            WhT[n * 256 + 128 + k] = f2b(Wr[idx]);
        }
        return;
    }

    // ---- binA: block-local counting sort into global bucket runs
    const int e0 = blk * EPB;
    const int n = min(EPB, N_EDGES - e0);

    for (int i = tid; i < NBUCK; i += 256) hist[i] = 0;
    __syncthreads();
    for (int i = tid; i < n; i += 256)
        atomicAdd(&hist[dst[e0 + i] >> 6], 1);
    __syncthreads();
    if (tid < 64) {                          // excl. scan of hist[0..781]
        int c0 = tid * 13;
        int v[13];
        int s = 0;
        #pragma unroll
        for (int j = 0; j < 13; ++j) {
            int idx = c0 + j;
            v[j] = (idx < NBUCK) ? hist[idx] : 0;
            s += v[j];
        }
        int incl = s;
        #pragma unroll
        for (int d = 1; d < 64; d <<= 1) {
            int t = __shfl_up(incl, d, 64);
            if (tid >= d) incl += t;
        }
        int run = incl - s;
        #pragma unroll
        for (int j = 0; j < 13; ++j) {
            int idx = c0 + j;
            if (idx < NBUCK) lbase[idx] = run;
            run += v[j];
        }
    }
    __syncthreads();
    for (int i = tid; i < NBUCK; i += 256) {
        int c = hist[i];
        gbase[i] = i * SLACK + (c ? atomicAdd(&gcur[i], c) : 0);
        hist[i] = 0;                         // reuse as rank cursor
    }
    __syncthreads();
    for (int i = tid; i < n; i += 256) {
        int d = dst[e0 + i];
        int s = src[e0 + i];
        int b = d >> 6;
        int r = atomicAdd(&hist[b], 1);
        img[lbase[b] + r] = (unsigned int)s | ((unsigned int)d << 16);
    }
    __syncthreads();
    for (int i = tid; i < n; i += 256) {
        unsigned int v = img[i];
        int b = (int)(v >> 16) >> 6;
        int pos = gbase[b] + (i - lbase[b]);
        if (pos < (b + 1) * SLACK) buf[pos] = v;   // overflow drops, not corrupts
    }
}

// ---------------- binBC: LDS CSR + pair-gather-mean + MFMA GEMM + LN + ReLU ----
// (identical to the R11 verified configuration)
__global__ __launch_bounds__(256) void binBC_kernel(
    const unsigned int* __restrict__ buf,
    const int* __restrict__ gcur,
    const unsigned short* __restrict__ xh,
    const unsigned short* __restrict__ WhT,
    const float* __restrict__ bl,
    const float* __restrict__ gamma,
    const float* __restrict__ beta,
    float* __restrict__ out)
{
    __shared__ unsigned int ebuf[SLACK];              // 5,120 B packed edges
    __shared__ unsigned short csr[SLACK + 16];        // 2,592 B local CSR, zeroed
    __shared__ int dhist[BNODES];
    __shared__ int dbase[BNODES];
    __shared__ int dcur[BNODES];
    __shared__ unsigned short aggh[M_TILE][DIM + 8];  // 8,704 B bf16 agg tile
    __shared__ float sRed[M_TILE][4][2];              // 1,024 B LN partials

    const int tid = threadIdx.x;
    const int w = tid >> 6;
    const int lane = tid & 63;
    const int r16 = lane & 15;
    const int kg = lane >> 4;
    const int b = blockIdx.x / SPLIT;            // bucket
    const int half = blockIdx.x % SPLIT;         // node slice
    const int rb = blockIdx.x * M_TILE;          // global row base
    const int cnt = min(gcur[b], SLACK);
    const unsigned int* bp = buf + (size_t)b * SLACK;

    // ---- local CSR build (bucket-wide, 64 nodes); csr zero-init for safe clamp
    if (tid < BNODES) { dhist[tid] = 0; dcur[tid] = 0; }
    for (int i = tid; i < (SLACK + 16) / 2; i += 256)
        reinterpret_cast<unsigned int*>(csr)[i] = 0;
    for (int i = tid; i < cnt; i += 256) ebuf[i] = bp[i];
    __syncthreads();
    for (int i = tid; i < cnt; i += 256)
        atomicAdd(&dhist[(ebuf[i] >> 16) & 63], 1);
    __syncthreads();
    if (tid < 64) {                              // scan 64 degree values
        int v = dhist[tid];
        int incl = v;
        #pragma unroll
        for (int d = 1; d < 64; d <<= 1) {
            int t = __shfl_up(incl, d, 64);
            if (tid >= d) incl += t;
        }
        dbase[tid] = incl - v;
    }
    __syncthreads();
    for (int i = tid; i < cnt; i += 256) {
        unsigned int v = ebuf[i];
        int d = (v >> 16) & 63;
        int r = atomicAdd(&dcur[d], 1);
        csr[dbase[d] + r] = (unsigned short)(v & 0xFFFFu);
    }
    __syncthreads();

    // ---- pair-gather: wave w does rows {w+8j, w+8j+4}; 32 loads in flight
    const unsigned int* xp = reinterpret_cast<const unsigned int*>(xh);
    for (int j = 0; j < M_TILE / 8; ++j) {
        int lnlA = w + 8 * j;
        int lnlB = lnlA + 4;
        int lnA = half * M_TILE + lnlA;
        int lnB = half * M_TILE + lnlB;
        int nodeA = b * BNODES + lnA;
        int nodeB = b * BNODES + lnB;
        int degA = (nodeA < N_NODES) ? dhist[lnA] : 0;
        int degB = (nodeB < N_NODES) ? dhist[lnB] : 0;
        int stA = dbase[lnA], stB = dbase[lnB];
        int dmA = max(degA - 1, 0), dmB = max(degB - 1, 0);
        float axA = 0.f, ayA = 0.f, axB = 0.f, ayB = 0.f;

        unsigned int vA[16], vB[16];
        #pragma unroll
        for (int t = 0; t < 16; ++t)
            vA[t] = xp[csr[stA + min(t, dmA)] * 64 + lane];
        #pragma unroll
        for (int t = 0; t < 16; ++t)
            vB[t] = xp[csr[stB + min(t, dmB)] * 64 + lane];
        #pragma unroll
        for (int t = 0; t < 16; ++t) {
            if (t < degA) { axA += blo(vA[t]); ayA += bhi(vA[t]); }
            if (t < degB) { axB += blo(vB[t]); ayB += bhi(vB[t]); }
        }
        for (int base = 16; base < degA; base += 8) {
            unsigned int u[8];
            #pragma unroll
            for (int t = 0; t < 8; ++t)
                u[t] = xp[csr[stA + min(base + t, dmA)] * 64 + lane];
            #pragma unroll
            for (int t = 0; t < 8; ++t)
                if (base + t < degA) { axA += blo(u[t]); ayA += bhi(u[t]); }
        }
        for (int base = 16; base < degB; base += 8) {
            unsigned int u[8];
            #pragma unroll
            for (int t = 0; t < 8; ++t)
                u[t] = xp[csr[stB + min(base + t, dmB)] * 64 + lane];
            #pragma unroll
            for (int t = 0; t < 8; ++t)
                if (base + t < degB) { axB += blo(u[t]); ayB += bhi(u[t]); }
        }
        float invA = 1.0f / (float)max(degA, 1);
        float invB = 1.0f / (float)max(degB, 1);
        unsigned int pkA = (unsigned int)f2b(axA * invA)
                         | ((unsigned int)f2b(ayA * invA) << 16);
        unsigned int pkB = (unsigned int)f2b(axB * invB)
                         | ((unsigned int)f2b(ayB * invB) << 16);
        *reinterpret_cast<unsigned int*>(&aggh[lnlA][lane * 2]) = pkA;
        *reinterpret_cast<unsigned int*>(&aggh[lnlB][lane * 2]) = pkB;
    }
    __syncthreads();

    // ---- MFMA GEMM: 32 rows x 128 cols, K=256 (A: LDS agg ++ own xh rows)
    f32x4 acc[MW][2];
    #pragma unroll
    for (int m = 0; m < MW; ++m)
        #pragma unroll
        for (int f = 0; f < 2; ++f)
            acc[m][f] = (f32x4){0.f, 0.f, 0.f, 0.f};

    #pragma unroll
    for (int kf = 0; kf < 8; ++kf) {
        bf16x8 a[MW];
        bf16x8 bfk[2];
        #pragma unroll
        for (int f = 0; f < 2; ++f)
            bfk[f] = *reinterpret_cast<const bf16x8*>(
                WhT + (w * 32 + f * 16 + r16) * 256 + kf * 32 + kg * 8);
        if (kf < 4) {
            #pragma unroll
            for (int m = 0; m < MW; ++m)
                a[m] = *reinterpret_cast<const bf16x8*>(
                    &aggh[m * 16 + r16][kf * 32 + kg * 8]);
        } else {
            #pragma unroll
            for (int m = 0; m < MW; ++m)
                a[m] = *reinterpret_cast<const bf16x8*>(
                    xh + (size_t)(rb + m * 16 + r16) * DIM + (kf - 4) * 32 + kg * 8);
        }
        #pragma unroll
        for (int m = 0; m < MW; ++m)
            #pragma unroll
            for (int f = 0; f < 2; ++f)
                acc[m][f] = __builtin_amdgcn_mfma_f32_16x16x32_bf16(
                    a[m], bfk[f], acc[m][f], 0, 0, 0);
    }

    // ---- bias + LayerNorm + ReLU epilogue
    float blv[2], gav[2], bev[2];
    #pragma unroll
    for (int f = 0; f < 2; ++f) {
        int col = w * 32 + f * 16 + r16;
        blv[f] = bl[col]; gav[f] = gamma[col]; bev[f] = beta[col];
    }
    #pragma unroll
    for (int m = 0; m < MW; ++m)
        #pragma unroll
        for (int r = 0; r < 4; ++r) {
            float v0 = acc[m][0][r] + blv[0];
            float v1 = acc[m][1][r] + blv[1];
            acc[m][0][r] = v0; acc[m][1][r] = v1;
            float s = v0 + v1;
            float q = v0 * v0 + v1 * v1;
            #pragma unroll
            for (int d = 1; d < 16; d <<= 1) {
                s += __shfl_xor(s, d, 16);
                q += __shfl_xor(q, d, 16);
            }
            if (r16 == 0) {
                sRed[m * 16 + kg * 4 + r][w][0] = s;
                sRed[m * 16 + kg * 4 + r][w][1] = q;
            }
        }
    __syncthreads();

    #pragma unroll
    for (int m = 0; m < MW; ++m)
        #pragma unroll
        for (int r = 0; r < 4; ++r) {
            int lr = m * 16 + kg * 4 + r;
            float S = sRed[lr][0][0] + sRed[lr][1][0] + sRed[lr][2][0] + sRed[lr][3][0];
            float Q = sRed[lr][0][1] + sRed[lr][1][1] + sRed[lr][2][1] + sRed[lr][3][1];
            float mean = S * (1.0f / 128.0f);
            float var = Q * (1.0f / 128.0f) - mean * mean;
            float rstd = rsqrtf(var + 1e-5f);
            int row = rb + lr;
            if (row < N_NODES) {
                #pragma unroll
                for (int f = 0; f < 2; ++f) {
                    float o = (acc[m][f][r] - mean) * rstd * gav[f] + bev[f];
                    out[(size_t)row * DIM + w * 32 + f * 16 + r16] = fmaxf(o, 0.f);
                }
            }
        }
}

extern "C" void kernel_launch(void* const* d_in, const int* in_sizes, int n_in,
                              void* d_out, int out_size, void* d_ws, size_t ws_size,
                              hipStream_t stream) {
    const float* x     = (const float*)d_in[0];
    const int*   ei    = (const int*)d_in[1];
    const float* Wl    = (const float*)d_in[2];
    const float* bl    = (const float*)d_in[3];
    const float* Wr    = (const float*)d_in[4];
    const float* gamma = (const float*)d_in[5];
    const float* beta  = (const float*)d_in[6];
    float* out = (float*)d_out;
    int*           gcur = (int*)d_ws;
    unsigned int*  buf  = (unsigned int*)((char*)d_ws + WS_BUF_OFF);
    unsigned short* xh  = (unsigned short*)((char*)d_ws + WS_XH_OFF);
    unsigned short* WhT = (unsigned short*)((char*)d_ws + WS_WT_OFF);

    const int* src = ei;
    const int* dst = ei + N_EDGES;

    (void)hipMemsetAsync(gcur, 0, 1024 * sizeof(int), stream);

    prepA_kernel<<<NBLKA + CAST_BLOCKS + WT_BLOCKS, 256, 0, stream>>>(
        x, Wl, Wr, src, dst, xh, WhT, gcur, buf);
    binBC_kernel<<<NBUCK * SPLIT, 256, 0, stream>>>(
        buf, gcur, xh, WhT, bl, gamma, beta, out);
}

// Round 14
// 76.670 us; speedup vs baseline: 1.2430x; 1.0172x over previous
//
#include <hip/hip_runtime.h>

#define N_NODES 50000
#define N_EDGES 800000
#define DIM 128
#define M_PAD 50048                 // 1564 binBC blocks * 32 rows

#define BNODES 64                   // nodes per bucket (dst>>6)
#define NBUCK 782                   // ceil(N_NODES / 64)
#define SLACK 1280                  // per-bucket capacity (mean 1023, sigma 32)
#define EPB   4096                  // edges per binA block
#define NBLKA ((N_EDGES + EPB - 1) / EPB)   // 196
#define SPLIT 2                     // binBC blocks per bucket
#define HCAP  784                   // half-bucket csr capacity (mean 512 + 12 sigma)

#define M_TILE 32                   // binBC: rows per block
#define MW 2                        // binBC: 16-row m-frags per wave

typedef __attribute__((ext_vector_type(8))) short bf16x8;
typedef __attribute__((ext_vector_type(4))) float f32x4;

// ws layout (bytes):
//   int gcur[1024]                    @ 0            (4,096)
//   u32 buf[NBUCK*SLACK]              @ 4,096        (4,003,840)
//   bf16 xh[M_PAD][128]               @ 4,007,936    (12,812,288)
//   bf16 WhT[128][256]                @ 16,820,224   (65,536)   -> total 16.9 MB
#define WS_BUF_OFF 4096
#define WS_XH_OFF  (WS_BUF_OFF + (size_t)NBUCK * SLACK * 4)
#define WS_WT_OFF  (WS_XH_OFF + (size_t)M_PAD * DIM * 2)

static __device__ __forceinline__ unsigned short f2b(float f) {
    unsigned int x = __float_as_uint(f);
    x += 0x7fffu + ((x >> 16) & 1u);
    return (unsigned short)(x >> 16);
}
static __device__ __forceinline__ float blo(unsigned int v) {
    return __uint_as_float(v << 16);
}
static __device__ __forceinline__ float bhi(unsigned int v) {
    return __uint_as_float(v & 0xffff0000u);
}

// ---------------- prepA: binA (blocks 0..195, starts first) + cast + WhT -------
#define N_F4 (N_NODES * DIM / 4)    // 1,600,000 float4s
#define CAST_BLOCKS 1563            // ceil(N_F4 / 1024)
#define WT_BLOCKS 64

__global__ __launch_bounds__(256) void prepA_kernel(
    const float* __restrict__ x,
    const float* __restrict__ Wl,
    const float* __restrict__ Wr,
    const int* __restrict__ src,
    const int* __restrict__ dst,
    unsigned short* __restrict__ xh,
    unsigned short* __restrict__ WhT,
    int* __restrict__ gcur,
    unsigned int* __restrict__ buf)
{
    __shared__ unsigned int img[EPB];        // 16 KB (binA blocks only)
    __shared__ int hist[NBUCK];
    __shared__ int lbase[NBUCK];
    __shared__ int gbase[NBUCK];

    const int blk = blockIdx.x;
    const int tid = threadIdx.x;

    if (blk >= NBLKA) {
        int b = blk - NBLKA;
        if (b < CAST_BLOCKS) {               // cast x -> bf16, 4 f4 per thread
            int base = b * 1024 + tid;
            #pragma unroll
            for (int r = 0; r < 4; ++r) {
                int i = base + r * 256;
                if (i < N_F4) {
                    float4 v = reinterpret_cast<const float4*>(x)[i];
                    ushort4 h;
                    h.x = f2b(v.x); h.y = f2b(v.y); h.z = f2b(v.z); h.w = f2b(v.w);
                    reinterpret_cast<ushort4*>(xh)[i] = h;
                }
            }
        } else {                             // build WhT
            int idx = (b - CAST_BLOCKS) * 256 + tid;   // k*128+n over [128][128]
            int n = idx & 127;
            int k = idx >> 7;
            WhT[n * 256 + k]       = f2b(Wl[idx]);
            WhT[n * 256 + 128 + k] = f2b(Wr[idx]);
        }
        return;
    }

    // ---- binA: block-local counting sort into global bucket runs
    const int e0 = blk * EPB;
    const int n = min(EPB, N_EDGES - e0);

    for (int i = tid; i < NBUCK; i += 256) hist[i] = 0;
    __syncthreads();
    for (int i = tid; i < n; i += 256)
        atomicAdd(&hist[dst[e0 + i] >> 6], 1);
    __syncthreads();
    if (tid < 64) {                          // excl. scan of hist[0..781]
        int c0 = tid * 13;
        int v[13];
        int s = 0;
        #pragma unroll
        for (int j = 0; j < 13; ++j) {
            int idx = c0 + j;
            v[j] = (idx < NBUCK) ? hist[idx] : 0;
            s += v[j];
        }
        int incl = s;
        #pragma unroll
        for (int d = 1; d < 64; d <<= 1) {
            int t = __shfl_up(incl, d, 64);
            if (tid >= d) incl += t;
        }
        int run = incl - s;
        #pragma unroll
        for (int j = 0; j < 13; ++j) {
            int idx = c0 + j;
            if (idx < NBUCK) lbase[idx] = run;
            run += v[j];
        }
    }
    __syncthreads();
    for (int i = tid; i < NBUCK; i += 256) {
        int c = hist[i];
        gbase[i] = i * SLACK + (c ? atomicAdd(&gcur[i], c) : 0);
        hist[i] = 0;                         // reuse as rank cursor
    }
    __syncthreads();
    for (int i = tid; i < n; i += 256) {
        int d = dst[e0 + i];
        int s = src[e0 + i];
        int b = d >> 6;
        int r = atomicAdd(&hist[b], 1);
        img[lbase[b] + r] = (unsigned int)s | ((unsigned int)d << 16);
    }
    __syncthreads();
    for (int i = tid; i < n; i += 256) {
        unsigned int v = img[i];
        int b = (int)(v >> 16) >> 6;
        int pos = gbase[b] + (i - lbase[b]);
        if (pos < (b + 1) * SLACK) buf[pos] = v;   // overflow drops, not corrupts
    }
}

// ---------------- binBC: half-filtered LDS CSR + pair-gather + MFMA + LN -------
__global__ __launch_bounds__(256) void binBC_kernel(
    const unsigned int* __restrict__ buf,
    const int* __restrict__ gcur,
    const unsigned short* __restrict__ xh,
    const unsigned short* __restrict__ WhT,
    const float* __restrict__ bl,
    const float* __restrict__ gamma,
    const float* __restrict__ beta,
    float* __restrict__ out)
{
    __shared__ unsigned int ebuf[SLACK];              // 5,120 B packed edges
    __shared__ unsigned short csr[HCAP + 16];         // 1,600 B own-half CSR
    __shared__ int dhist[M_TILE];                     // per-node degree (own half)
    __shared__ int dbase[M_TILE];
    __shared__ int dcur[M_TILE];
    __shared__ unsigned short aggh[M_TILE][DIM + 8];  // 8,704 B bf16 agg tile
    __shared__ float sRed[M_TILE][4][2];              // 1,024 B LN partials

    const int tid = threadIdx.x;
    const int w = tid >> 6;
    const int lane = tid & 63;
    const int r16 = lane & 15;
    const int kg = lane >> 4;
    const int b = blockIdx.x / SPLIT;            // bucket
    const int half = blockIdx.x % SPLIT;         // node slice (0/1)
    const int rb = blockIdx.x * M_TILE;          // global row base
    const int cnt = min(gcur[b], SLACK);
    const unsigned int* bp = buf + (size_t)b * SLACK;

    // ---- own-half CSR build: only edges with ((v>>21)&1) == half
    if (tid < M_TILE) { dhist[tid] = 0; dcur[tid] = 0; }
    for (int i = tid; i < (HCAP + 16) / 2; i += 256)
        reinterpret_cast<unsigned int*>(csr)[i] = 0;
    for (int i = tid; i < cnt; i += 256) ebuf[i] = bp[i];
    __syncthreads();
    for (int i = tid; i < cnt; i += 256) {
        unsigned int v = ebuf[i];
        if ((int)((v >> 21) & 1u) == half)
            atomicAdd(&dhist[(v >> 16) & 31], 1);
    }
    __syncthreads();
    if (tid < 32) {                              // scan 32 degree values
        int v = dhist[tid];
        int incl = v;
        #pragma unroll
        for (int d = 1; d < 32; d <<= 1) {
            int t = __shfl_up(incl, d, 32);
            if (tid >= d) incl += t;
        }
        dbase[tid] = incl - v;
    }
    __syncthreads();
    for (int i = tid; i < cnt; i += 256) {
        unsigned int v = ebuf[i];
        if ((int)((v >> 21) & 1u) == half) {
            int d = (v >> 16) & 31;
            int r = atomicAdd(&dcur[d], 1);
            int pos = dbase[d] + r;
            if (pos < HCAP) csr[pos] = (unsigned short)(v & 0xFFFFu);
        }
    }
    __syncthreads();

    // ---- pair-gather: wave w does rows {w+8j, w+8j+4}; fused tails
    const unsigned int* xp = reinterpret_cast<const unsigned int*>(xh);
    for (int j = 0; j < M_TILE / 8; ++j) {
        int lnlA = w + 8 * j;
        int lnlB = lnlA + 4;
        int nodeA = b * BNODES + half * M_TILE + lnlA;
        int nodeB = b * BNODES + half * M_TILE + lnlB;
        int degA = (nodeA < N_NODES) ? dhist[lnlA] : 0;
        int degB = (nodeB < N_NODES) ? dhist[lnlB] : 0;
        int stA = dbase[lnlA], stB = dbase[lnlB];
        int dmA = max(degA - 1, 0), dmB = max(degB - 1, 0);
        float axA = 0.f, ayA = 0.f, axB = 0.f, ayB = 0.f;

        unsigned int vA[16], vB[16];
        #pragma unroll
        for (int t = 0; t < 16; ++t)
            vA[t] = xp[csr[stA + min(t, dmA)] * 64 + lane];
        #pragma unroll
        for (int t = 0; t < 16; ++t)
            vB[t] = xp[csr[stB + min(t, dmB)] * 64 + lane];
        #pragma unroll
        for (int t = 0; t < 16; ++t) {
            if (t < degA) { axA += blo(vA[t]); ayA += bhi(vA[t]); }
            if (t < degB) { axB += blo(vB[t]); ayB += bhi(vB[t]); }
        }
        // fused tails: one round trip covers both nodes' extra batches
        int tmax = max(degA, degB);
        for (int base = 16; base < tmax; base += 8) {
            unsigned int uA[8], uB[8];
            #pragma unroll
            for (int t = 0; t < 8; ++t)
                uA[t] = xp[csr[stA + min(base + t, dmA)] * 64 + lane];
            #pragma unroll
            for (int t = 0; t < 8; ++t)
                uB[t] = xp[csr[stB + min(base + t, dmB)] * 64 + lane];
            #pragma unroll
            for (int t = 0; t < 8; ++t) {
                if (base + t < degA) { axA += blo(uA[t]); ayA += bhi(uA[t]); }
                if (base + t < degB) { axB += blo(uB[t]); ayB += bhi(uB[t]); }
            }
        }
        float invA = 1.0f / (float)max(degA, 1);
        float invB = 1.0f / (float)max(degB, 1);
        unsigned int pkA = (unsigned int)f2b(axA * invA)
                         | ((unsigned int)f2b(ayA * invA) << 16);
        unsigned int pkB = (unsigned int)f2b(axB * invB)
                         | ((unsigned int)f2b(ayB * invB) << 16);
        *reinterpret_cast<unsigned int*>(&aggh[lnlA][lane * 2]) = pkA;
        *reinterpret_cast<unsigned int*>(&aggh[lnlB][lane * 2]) = pkB;
    }
    __syncthreads();

    // ---- MFMA GEMM: 32 rows x 128 cols, K=256 (A: LDS agg ++ own xh rows)
    f32x4 acc[MW][2];
    #pragma unroll
    for (int m = 0; m < MW; ++m)
        #pragma unroll
        for (int f = 0; f < 2; ++f)
            acc[m][f] = (f32x4){0.f, 0.f, 0.f, 0.f};

    #pragma unroll
    for (int kf = 0; kf < 8; ++kf) {
        bf16x8 a[MW];
        bf16x8 bfk[2];
        #pragma unroll
        for (int f = 0; f < 2; ++f)
            bfk[f] = *reinterpret_cast<const bf16x8*>(
                WhT + (w * 32 + f * 16 + r16) * 256 + kf * 32 + kg * 8);
        if (kf < 4) {
            #pragma unroll
            for (int m = 0; m < MW; ++m)
                a[m] = *reinterpret_cast<const bf16x8*>(
                    &aggh[m * 16 + r16][kf * 32 + kg * 8]);
        } else {
            #pragma unroll
            for (int m = 0; m < MW; ++m)
                a[m] = *reinterpret_cast<const bf16x8*>(
                    xh + (size_t)(rb + m * 16 + r16) * DIM + (kf - 4) * 32 + kg * 8);
        }
        #pragma unroll
        for (int m = 0; m < MW; ++m)
            #pragma unroll
            for (int f = 0; f < 2; ++f)
                acc[m][f] = __builtin_amdgcn_mfma_f32_16x16x32_bf16(
                    a[m], bfk[f], acc[m][f], 0, 0, 0);
    }

    // ---- bias + LayerNorm + ReLU epilogue (non-temporal out stores)
    float blv[2], gav[2], bev[2];
    #pragma unroll
    for (int f = 0; f < 2; ++f) {
        int col = w * 32 + f * 16 + r16;
        blv[f] = bl[col]; gav[f] = gamma[col]; bev[f] = beta[col];
    }
    #pragma unroll
    for (int m = 0; m < MW; ++m)
        #pragma unroll
        for (int r = 0; r < 4; ++r) {
            float v0 = acc[m][0][r] + blv[0];
            float v1 = acc[m][1][r] + blv[1];
            acc[m][0][r] = v0; acc[m][1][r] = v1;
            float s = v0 + v1;
            float q = v0 * v0 + v1 * v1;
            #pragma unroll
            for (int d = 1; d < 16; d <<= 1) {
                s += __shfl_xor(s, d, 16);
                q += __shfl_xor(q, d, 16);
            }
            if (r16 == 0) {
                sRed[m * 16 + kg * 4 + r][w][0] = s;
                sRed[m * 16 + kg * 4 + r][w][1] = q;
            }
        }
    __syncthreads();

    #pragma unroll
    for (int m = 0; m < MW; ++m)
        #pragma unroll
        for (int r = 0; r < 4; ++r) {
            int lr = m * 16 + kg * 4 + r;
            float S = sRed[lr][0][0] + sRed[lr][1][0] + sRed[lr][2][0] + sRed[lr][3][0];
            float Q = sRed[lr][0][1] + sRed[lr][1][1] + sRed[lr][2][1] + sRed[lr][3][1];
            float mean = S * (1.0f / 128.0f);
            float var = Q * (1.0f / 128.0f) - mean * mean;
            float rstd = rsqrtf(var + 1e-5f);
            int row = rb + lr;
            if (row < N_NODES) {
                #pragma unroll
                for (int f = 0; f < 2; ++f) {
                    float o = (acc[m][f][r] - mean) * rstd * gav[f] + bev[f];
                    __builtin_nontemporal_store(
                        fmaxf(o, 0.f),
                        out + (size_t)row * DIM + w * 32 + f * 16 + r16);
                }
            }
        }
}

extern "C" void kernel_launch(void* const* d_in, const int* in_sizes, int n_in,
                              void* d_out, int out_size, void* d_ws, size_t ws_size,
                              hipStream_t stream) {
    const float* x     = (const float*)d_in[0];
    const int*   ei    = (const int*)d_in[1];
    const float* Wl    = (const float*)d_in[2];
    const float* bl    = (const float*)d_in[3];
    const float* Wr    = (const float*)d_in[4];
    const float* gamma = (const float*)d_in[5];
    const float* beta  = (const float*)d_in[6];
    float* out = (float*)d_out;
    int*           gcur = (int*)d_ws;
    unsigned int*  buf  = (unsigned int*)((char*)d_ws + WS_BUF_OFF);
    unsigned short* xh  = (unsigned short*)((char*)d_ws + WS_XH_OFF);
    unsigned short* WhT = (unsigned short*)((char*)d_ws + WS_WT_OFF);

    const int* src = ei;
    const int* dst = ei + N_EDGES;

    (void)hipMemsetAsync(gcur, 0, 1024 * sizeof(int), stream);

    prepA_kernel<<<NBLKA + CAST_BLOCKS + WT_BLOCKS, 256, 0, stream>>>(
        x, Wl, Wr, src, dst, xh, WhT, gcur, buf);
    binBC_kernel<<<NBUCK * SPLIT, 256, 0, stream>>>(
        buf, gcur, xh, WhT, bl, gamma, beta, out);
}

// Round 15
// 70.674 us; speedup vs baseline: 1.3485x; 1.0848x over previous
//
#include <hip/hip_runtime.h>

#define N_NODES 50000
#define N_EDGES 800000
#define DIM 128
#define M_PAD 50048                 // 1564 binBC blocks * 32 rows

#define BNODES 64                   // nodes per bucket (dst>>6)
#define NBUCK 782                   // ceil(N_NODES / 64)
#define SLACK 1280                  // per-bucket capacity (mean 1023, sigma 32)
#define EPB   4096                  // edges per binA block
#define NBLKA ((N_EDGES + EPB - 1) / EPB)   // 196
#define SPLIT 2                     // binBC blocks per bucket
#define HCAP  784                   // half-bucket csr capacity (mean 512 + 12 sigma)

#define M_TILE 32                   // binBC: rows per block
#define MW 2                        // binBC: 16-row m-frags per wave

typedef __attribute__((ext_vector_type(8))) short bf16x8;
typedef __attribute__((ext_vector_type(4))) float f32x4;

// ws layout (bytes):
//   int gcur[1024]                    @ 0            (4,096)
//   u32 buf[NBUCK*SLACK]              @ 4,096        (4,003,840)
//   bf16 xh[M_PAD][128]               @ 4,007,936    (12,812,288)
//   bf16 WhT[128][256]                @ 16,820,224   (65,536)   -> total 16.9 MB
#define WS_BUF_OFF 4096
#define WS_XH_OFF  (WS_BUF_OFF + (size_t)NBUCK * SLACK * 4)
#define WS_WT_OFF  (WS_XH_OFF + (size_t)M_PAD * DIM * 2)

static __device__ __forceinline__ unsigned short f2b(float f) {
    unsigned int x = __float_as_uint(f);
    x += 0x7fffu + ((x >> 16) & 1u);
    return (unsigned short)(x >> 16);
}
static __device__ __forceinline__ float blo(unsigned int v) {
    return __uint_as_float(v << 16);
}
static __device__ __forceinline__ float bhi(unsigned int v) {
    return __uint_as_float(v & 0xffff0000u);
}

// ---------------- prepA (1024 threads): binA first + cast + WhT ----------------
// binA at 1024 thr = 16 waves/CU during binning -> latency hidden by TLP.
#define N_F4 (N_NODES * DIM / 4)    // 1,600,000 float4s
#define CAST_BLOCKS 391             // ceil(N_F4 / 4096), 4 float4 per thread
#define WT_BLOCKS 16                // 16384 / 1024

__global__ __launch_bounds__(1024) void prepA_kernel(
    const float* __restrict__ x,
    const float* __restrict__ Wl,
    const float* __restrict__ Wr,
    const int* __restrict__ src,
    const int* __restrict__ dst,
    unsigned short* __restrict__ xh,
    unsigned short* __restrict__ WhT,
    int* __restrict__ gcur,
    unsigned int* __restrict__ buf)
{
    __shared__ unsigned int img[EPB];        // 16 KB (binA blocks only)
    __shared__ int hist[NBUCK];
    __shared__ int lbase[NBUCK];
    __shared__ int gbase[NBUCK];
    __shared__ int swsum[16];

    const int blk = blockIdx.x;
    const int tid = threadIdx.x;

    if (blk >= NBLKA) {
        int b = blk - NBLKA;
        if (b < CAST_BLOCKS) {               // cast x -> bf16, 4 f4 per thread
            int base = b * 4096 + tid;
            #pragma unroll
            for (int r = 0; r < 4; ++r) {
                int i = base + r * 1024;
                if (i < N_F4) {
                    float4 v = reinterpret_cast<const float4*>(x)[i];
                    ushort4 h;
                    h.x = f2b(v.x); h.y = f2b(v.y); h.z = f2b(v.z); h.w = f2b(v.w);
                    reinterpret_cast<ushort4*>(xh)[i] = h;
                }
            }
        } else {                             // build WhT
            int idx = (b - CAST_BLOCKS) * 1024 + tid;  // k*128+n over [128][128]
            int n = idx & 127;
            int k = idx >> 7;
            WhT[n * 256 + k]       = f2b(Wl[idx]);
            WhT[n * 256 + 128 + k] = f2b(Wr[idx]);
        }
        return;
    }

    // ---- binA: block-local counting sort into global bucket runs
    const int e0 = blk * EPB;
    const int n = min(EPB, N_EDGES - e0);
    const int lane = tid & 63;
    const int wv = tid >> 6;                 // 0..15

    for (int i = tid; i < NBUCK; i += 1024) hist[i] = 0;
    __syncthreads();
    for (int i = tid; i < n; i += 1024)
        atomicAdd(&hist[dst[e0 + i] >> 6], 1);
    __syncthreads();

    // two-level exclusive scan of hist[0..781] across all 1024 threads
    {
        int val = (tid < NBUCK) ? hist[tid] : 0;
        int incl = val;
        #pragma unroll
        for (int d = 1; d < 64; d <<= 1) {
            int t = __shfl_up(incl, d, 64);
            if (lane >= d) incl += t;
        }
        if (lane == 63) swsum[wv] = incl;
        __syncthreads();
        if (tid < 16) {
            int v = swsum[tid];
            #pragma unroll
            for (int d = 1; d < 16; d <<= 1) {
                int t = __shfl_up(v, d, 16);
                if (tid >= d) v += t;
            }
            swsum[tid] = v;                  // inclusive wave prefix
        }
        __syncthreads();
        int wbase = (wv > 0) ? swsum[wv - 1] : 0;
        if (tid < NBUCK) lbase[tid] = wbase + incl - val;
    }
    __syncthreads();
    for (int i = tid; i < NBUCK; i += 1024) {
        int c = hist[i];
        gbase[i] = i * SLACK + (c ? atomicAdd(&gcur[i], c) : 0);
        hist[i] = 0;                         // reuse as rank cursor
    }
    __syncthreads();
    for (int i = tid; i < n; i += 1024) {
        int d = dst[e0 + i];
        int s = src[e0 + i];
        int b = d >> 6;
        int r = atomicAdd(&hist[b], 1);
        img[lbase[b] + r] = (unsigned int)s | ((unsigned int)d << 16);
    }
    __syncthreads();
    for (int i = tid; i < n; i += 1024) {
        unsigned int v = img[i];
        int b = (int)(v >> 16) >> 6;
        int pos = gbase[b] + (i - lbase[b]);
        if (pos < (b + 1) * SLACK) buf[pos] = v;   // overflow drops, not corrupts
    }
}

// ---------------- binBC: half-filtered LDS CSR + pair-gather + MFMA + LN -------
// (identical to the R14 verified configuration)
__global__ __launch_bounds__(256) void binBC_kernel(
    const unsigned int* __restrict__ buf,
    const int* __restrict__ gcur,
    const unsigned short* __restrict__ xh,
    const unsigned short* __restrict__ WhT,
    const float* __restrict__ bl,
    const float* __restrict__ gamma,
    const float* __restrict__ beta,
    float* __restrict__ out)
{
    __shared__ unsigned int ebuf[SLACK];              // 5,120 B packed edges
    __shared__ unsigned short csr[HCAP + 16];         // 1,600 B own-half CSR
    __shared__ int dhist[M_TILE];                     // per-node degree (own half)
    __shared__ int dbase[M_TILE];
    __shared__ int dcur[M_TILE];
    __shared__ unsigned short aggh[M_TILE][DIM + 8];  // 8,704 B bf16 agg tile
    __shared__ float sRed[M_TILE][4][2];              // 1,024 B LN partials

    const int tid = threadIdx.x;
    const int w = tid >> 6;
    const int lane = tid & 63;
    const int r16 = lane & 15;
    const int kg = lane >> 4;
    const int b = blockIdx.x / SPLIT;            // bucket
    const int half = blockIdx.x % SPLIT;         // node slice (0/1)
    const int rb = blockIdx.x * M_TILE;          // global row base
    const int cnt = min(gcur[b], SLACK);
    const unsigned int* bp = buf + (size_t)b * SLACK;

    // ---- own-half CSR build: only edges with ((v>>21)&1) == half
    if (tid < M_TILE) { dhist[tid] = 0; dcur[tid] = 0; }
    for (int i = tid; i < (HCAP + 16) / 2; i += 256)
        reinterpret_cast<unsigned int*>(csr)[i] = 0;
    for (int i = tid; i < cnt; i += 256) ebuf[i] = bp[i];
    __syncthreads();
    for (int i = tid; i < cnt; i += 256) {
        unsigned int v = ebuf[i];
        if ((int)((v >> 21) & 1u) == half)
            atomicAdd(&dhist[(v >> 16) & 31], 1);
    }
    __syncthreads();
    if (tid < 32) {                              // scan 32 degree values
        int v = dhist[tid];
        int incl = v;
        #pragma unroll
        for (int d = 1; d < 32; d <<= 1) {
            int t = __shfl_up(incl, d, 32);
            if (tid >= d) incl += t;
        }
        dbase[tid] = incl - v;
    }
    __syncthreads();
    for (int i = tid; i < cnt; i += 256) {
        unsigned int v = ebuf[i];
        if ((int)((v >> 21) & 1u) == half) {
            int d = (v >> 16) & 31;
            int r = atomicAdd(&dcur[d], 1);
            int pos = dbase[d] + r;
            if (pos < HCAP) csr[pos] = (unsigned short)(v & 0xFFFFu);
        }
    }
    __syncthreads();

    // ---- pair-gather: wave w does rows {w+8j, w+8j+4}; fused tails
    const unsigned int* xp = reinterpret_cast<const unsigned int*>(xh);
    for (int j = 0; j < M_TILE / 8; ++j) {
        int lnlA = w + 8 * j;
        int lnlB = lnlA + 4;
        int nodeA = b * BNODES + half * M_TILE + lnlA;
        int nodeB = b * BNODES + half * M_TILE + lnlB;
        int degA = (nodeA < N_NODES) ? dhist[lnlA] : 0;
        int degB = (nodeB < N_NODES) ? dhist[lnlB] : 0;
        int stA = dbase[lnlA], stB = dbase[lnlB];
        int dmA = max(degA - 1, 0), dmB = max(degB - 1, 0);
        float axA = 0.f, ayA = 0.f, axB = 0.f, ayB = 0.f;

        unsigned int vA[16], vB[16];
        #pragma unroll
        for (int t = 0; t < 16; ++t)
            vA[t] = xp[csr[stA + min(t, dmA)] * 64 + lane];
        #pragma unroll
        for (int t = 0; t < 16; ++t)
            vB[t] = xp[csr[stB + min(t, dmB)] * 64 + lane];
        #pragma unroll
        for (int t = 0; t < 16; ++t) {
            if (t < degA) { axA += blo(vA[t]); ayA += bhi(vA[t]); }
            if (t < degB) { axB += blo(vB[t]); ayB += bhi(vB[t]); }
        }
        int tmax = max(degA, degB);
        for (int base = 16; base < tmax; base += 8) {
            unsigned int uA[8], uB[8];
            #pragma unroll
            for (int t = 0; t < 8; ++t)
                uA[t] = xp[csr[stA + min(base + t, dmA)] * 64 + lane];
            #pragma unroll
            for (int t = 0; t < 8; ++t)
                uB[t] = xp[csr[stB + min(base + t, dmB)] * 64 + lane];
            #pragma unroll
            for (int t = 0; t < 8; ++t) {
                if (base + t < degA) { axA += blo(uA[t]); ayA += bhi(uA[t]); }
                if (base + t < degB) { axB += blo(uB[t]); ayB += bhi(uB[t]); }
            }
        }
        float invA = 1.0f / (float)max(degA, 1);
        float invB = 1.0f / (float)max(degB, 1);
        unsigned int pkA = (unsigned int)f2b(axA * invA)
                         | ((unsigned int)f2b(ayA * invA) << 16);
        unsigned int pkB = (unsigned int)f2b(axB * invB)
                         | ((unsigned int)f2b(ayB * invB) << 16);
        *reinterpret_cast<unsigned int*>(&aggh[lnlA][lane * 2]) = pkA;
        *reinterpret_cast<unsigned int*>(&aggh[lnlB][lane * 2]) = pkB;
    }
    __syncthreads();

    // ---- MFMA GEMM: 32 rows x 128 cols, K=256 (A: LDS agg ++ own xh rows)
    f32x4 acc[MW][2];
    #pragma unroll
    for (int m = 0; m < MW; ++m)
        #pragma unroll
        for (int f = 0; f < 2; ++f)
            acc[m][f] = (f32x4){0.f, 0.f, 0.f, 0.f};

    #pragma unroll
    for (int kf = 0; kf < 8; ++kf) {
        bf16x8 a[MW];
        bf16x8 bfk[2];
        #pragma unroll
        for (int f = 0; f < 2; ++f)
            bfk[f] = *reinterpret_cast<const bf16x8*>(
                WhT + (w * 32 + f * 16 + r16) * 256 + kf * 32 + kg * 8);
        if (kf < 4) {
            #pragma unroll
            for (int m = 0; m < MW; ++m)
                a[m] = *reinterpret_cast<const bf16x8*>(
                    &aggh[m * 16 + r16][kf * 32 + kg * 8]);
        } else {
            #pragma unroll
            for (int m = 0; m < MW; ++m)
                a[m] = *reinterpret_cast<const bf16x8*>(
                    xh + (size_t)(rb + m * 16 + r16) * DIM + (kf - 4) * 32 + kg * 8);
        }
        #pragma unroll
        for (int m = 0; m < MW; ++m)
            #pragma unroll
            for (int f = 0; f < 2; ++f)
                acc[m][f] = __builtin_amdgcn_mfma_f32_16x16x32_bf16(
                    a[m], bfk[f], acc[m][f], 0, 0, 0);
    }

    // ---- bias + LayerNorm + ReLU epilogue (non-temporal out stores)
    float blv[2], gav[2], bev[2];
    #pragma unroll
    for (int f = 0; f < 2; ++f) {
        int col = w * 32 + f * 16 + r16;
        blv[f] = bl[col]; gav[f] = gamma[col]; bev[f] = beta[col];
    }
    #pragma unroll
    for (int m = 0; m < MW; ++m)
        #pragma unroll
        for (int r = 0; r < 4; ++r) {
            float v0 = acc[m][0][r] + blv[0];
            float v1 = acc[m][1][r] + blv[1];
            acc[m][0][r] = v0; acc[m][1][r] = v1;
            float s = v0 + v1;
            float q = v0 * v0 + v1 * v1;
            #pragma unroll
            for (int d = 1; d < 16; d <<= 1) {
                s += __shfl_xor(s, d, 16);
                q += __shfl_xor(q, d, 16);
            }
            if (r16 == 0) {
                sRed[m * 16 + kg * 4 + r][w][0] = s;
                sRed[m * 16 + kg * 4 + r][w][1] = q;
            }
        }
    __syncthreads();

    #pragma unroll
    for (int m = 0; m < MW; ++m)
        #pragma unroll
        for (int r = 0; r < 4; ++r) {
            int lr = m * 16 + kg * 4 + r;
            float S = sRed[lr][0][0] + sRed[lr][1][0] + sRed[lr][2][0] + sRed[lr][3][0];
            float Q = sRed[lr][0][1] + sRed[lr][1][1] + sRed[lr][2][1] + sRed[lr][3][1];
            float mean = S * (1.0f / 128.0f);
            float var = Q * (1.0f / 128.0f) - mean * mean;
            float rstd = rsqrtf(var + 1e-5f);
            int row = rb + lr;
            if (row < N_NODES) {
                #pragma unroll
                for (int f = 0; f < 2; ++f) {
                    float o = (acc[m][f][r] - mean) * rstd * gav[f] + bev[f];
                    __builtin_nontemporal_store(
                        fmaxf(o, 0.f),
                        out + (size_t)row * DIM + w * 32 + f * 16 + r16);
                }
            }
        }
}

extern "C" void kernel_launch(void* const* d_in, const int* in_sizes, int n_in,
                              void* d_out, int out_size, void* d_ws, size_t ws_size,
                              hipStream_t stream) {
    const float* x     = (const float*)d_in[0];
    const int*   ei    = (const int*)d_in[1];
    const float* Wl    = (const float*)d_in[2];
    const float* bl    = (const float*)d_in[3];
    const float* Wr    = (const float*)d_in[4];
    const float* gamma = (const float*)d_in[5];
    const float* beta  = (const float*)d_in[6];
    float* out = (float*)d_out;
    int*           gcur = (int*)d_ws;
    unsigned int*  buf  = (unsigned int*)((char*)d_ws + WS_BUF_OFF);
    unsigned short* xh  = (unsigned short*)((char*)d_ws + WS_XH_OFF);
    unsigned short* WhT = (unsigned short*)((char*)d_ws + WS_WT_OFF);

    const int* src = ei;
    const int* dst = ei + N_EDGES;

    (void)hipMemsetAsync(gcur, 0, 1024 * sizeof(int), stream);

    prepA_kernel<<<NBLKA + CAST_BLOCKS + WT_BLOCKS, 1024, 0, stream>>>(
        x, Wl, Wr, src, dst, xh, WhT, gcur, buf);
    binBC_kernel<<<NBUCK * SPLIT, 256, 0, stream>>>(
        buf, gcur, xh, WhT, bl, gamma, beta, out);
}